// Round 1
// 1455.199 us; speedup vs baseline: 4.3056x; 4.3056x over previous
//
#include <hip/hip_runtime.h>

#define Bq 2
#define Sq 2048
#define Hq 16
#define Dq 64
#define QT 64            // queries per block
#define KT 128           // keys per tile
#define NTILE (Sq/KT)    // 16

// async global->LDS, 16B per lane, LDS dest = wave-uniform base + lane*16
#define GLDS(gsrc, ldst) __builtin_amdgcn_global_load_lds( \
    (const __attribute__((address_space(1))) void*)(gsrc), \
    (__attribute__((address_space(3))) void*)(ldst), 16, 0, 0)

// Flash-style: block = (b,h,64-query tile), 8 waves x 8 queries.
// K/V tiles staged in LDS (XOR-swizzled, linear-dest gload_lds with
// pre-swizzled global source). Online softmax in registers. P transposed
// through wave-private LDS slice aliasing the dead K buffer.
__global__ __launch_bounds__(512, 4)
void attn_fwd(const float* __restrict__ q,
              const float* __restrict__ k,
              const float* __restrict__ v,
              const float* __restrict__ bias,
              const int* __restrict__ mask,
              float* __restrict__ out)
{
  __shared__ float qs[QT*Dq];   // 16 KB, linear, pre-scaled by sqrt(D)=8
  __shared__ float ks[KT*Dq];   // 32 KB, swizzled K; reused as P after QK
  __shared__ float vs[KT*Dq];   // 32 KB, swizzled V

  const int tid  = threadIdx.x;
  const int lane = tid & 63;
  const int wv   = tid >> 6;

  // XCD-contiguous remap (1024 blocks = 8 XCDs * 128): consecutive logical
  // blocks (same head -> shared K/V) land on the same XCD's L2.
  const int bid = (int)blockIdx.x;
  const int lid = ((bid & 7) << 7) | (bid >> 3);
  const int qt  = lid & 31;
  const int bh  = lid >> 5;
  const int h   = bh & (Hq - 1);
  const int b   = bh >> 4;
  const int q0  = qt * QT;
  const int qw  = q0 + wv*8;     // wave's first query row

  const float* qg = q + ((size_t)(b*Sq + q0)*Hq + h)*Dq;
  const float* kg = k + ((size_t)b*Sq*Hq + h)*Dq;          // + j*Hq*Dq per row
  const float* vg = v + ((size_t)b*Sq*Hq + h)*Dq;
  const float* bw = bias + ((size_t)((b*Hq + h)*Sq + qw))*Sq;
  const int*   mw = mask + ((size_t)(b*Sq + qw))*Sq;

  // ---- stage Q once (scaled by 8; reference MULTIPLIES q by sqrt(D)) ----
  #pragma unroll
  for (int r = 0; r < 2; ++r) {
    const int fo  = r*2048 + tid*4;
    const int row = fo >> 6, col = fo & 63;
    float4 t4 = *(const float4*)(qg + (size_t)row*(Hq*Dq) + col);
    t4.x *= 8.f; t4.y *= 8.f; t4.z *= 8.f; t4.w *= 8.f;
    *(float4*)(&qs[fo]) = t4;
  }

  float o[8][8];
  float m[8], l[8], s0[8], s1[8];
  #pragma unroll
  for (int qi = 0; qi < 8; ++qi) {
    m[qi] = -3.0e38f; l[qi] = 0.f;
    #pragma unroll
    for (int dd = 0; dd < 8; ++dd) o[qi][dd] = 0.f;
  }

  const int swf = (lane & 7) << 2;       // float-unit XOR swizzle for K rows
  const int g   = lane >> 3, c = lane & 7;
  const int vo0 = (c*8)     ^ (g << 2);  // V swizzle: row j has j&7 == g
  const int vo1 = (c*8 + 4) ^ (g << 2);
  float* pw = &ks[wv*1024];              // wave-private P: [8][128]

  for (int tt = 0; tt < NTILE; ++tt) {
    const int j0 = tt*KT;

    __syncthreads();   // previous tile (P reads, V reads) fully consumed

    // ---- stage K,V tile: linear LDS dest, inverse-swizzled global src ----
    #pragma unroll
    for (int r = 0; r < 4; ++r) {
      const int fo  = r*2048 + tid*4;
      const int row = fo >> 6;
      const int col = (fo & 63) ^ ((row & 7) << 2);
      GLDS(kg + (size_t)(j0 + row)*(Hq*Dq) + col, &ks[r*2048 + wv*256]);
      GLDS(vg + (size_t)(j0 + row)*(Hq*Dq) + col, &vs[r*2048 + wv*256]);
    }

    // ---- bias -> score accumulator init; mask -> bitfield (overlaps stage) ----
    const float* bb = bw + j0 + lane;
    const int*   mm = mw + j0 + lane;
    unsigned mb = 0;
    #pragma unroll
    for (int qi = 0; qi < 8; ++qi) {
      s0[qi] = bb[(size_t)qi*Sq];
      s1[qi] = bb[(size_t)qi*Sq + 64];
      if (mm[(size_t)qi*Sq])      mb |= 1u << (2*qi);
      if (mm[(size_t)qi*Sq + 64]) mb |= 2u << (2*qi);
    }

    __syncthreads();   // staging drained (syncthreads implies vmcnt(0))

    // ---- QK^T: lane -> keys (lane, lane+64); 8 queries register-blocked ----
    const float* kr0  = &ks[lane*64];
    const float* kr1  = &ks[(lane+64)*64];    // (lane+64)&7 == lane&7: same swizzle
    const float* qrow = &qs[wv*512];
    #pragma unroll 2
    for (int t = 0; t < 16; ++t) {
      const int off = (t*4) ^ swf;
      const float4 ka = *(const float4*)(kr0 + off);
      const float4 kb = *(const float4*)(kr1 + off);
      #pragma unroll
      for (int qi = 0; qi < 8; ++qi) {
        const float4 qv = *(const float4*)(qrow + qi*64 + t*4);  // broadcast
        s0[qi] = fmaf(qv.x, ka.x, s0[qi]);
        s0[qi] = fmaf(qv.y, ka.y, s0[qi]);
        s0[qi] = fmaf(qv.z, ka.z, s0[qi]);
        s0[qi] = fmaf(qv.w, ka.w, s0[qi]);
        s1[qi] = fmaf(qv.x, kb.x, s1[qi]);
        s1[qi] = fmaf(qv.y, kb.y, s1[qi]);
        s1[qi] = fmaf(qv.z, kb.z, s1[qi]);
        s1[qi] = fmaf(qv.w, kb.w, s1[qi]);
      }
    }

    // masked positions -> exact 0 (reference semantics, NOT -inf)
    #pragma unroll
    for (int qi = 0; qi < 8; ++qi) {
      if (mb & (1u << (2*qi))) s0[qi] = 0.f;
      if (mb & (2u << (2*qi))) s1[qi] = 0.f;
    }

    // ---- online softmax update ----
    #pragma unroll
    for (int qi = 0; qi < 8; ++qi) {
      float tm = fmaxf(s0[qi], s1[qi]);
      #pragma unroll
      for (int off = 32; off; off >>= 1) tm = fmaxf(tm, __shfl_xor(tm, off, 64));
      const float mn = fmaxf(m[qi], tm);
      const float sc = __expf(m[qi] - mn);   // first tile: expf(-3e38)=0
      const float p0 = __expf(s0[qi] - mn);
      const float p1 = __expf(s1[qi] - mn);
      float ls = p0 + p1;
      #pragma unroll
      for (int off = 32; off; off >>= 1) ls += __shfl_xor(ls, off, 64);
      l[qi] = l[qi]*sc + ls;
      m[qi] = mn;
      s0[qi] = p0; s1[qi] = p1;              // reuse score regs as P
      #pragma unroll
      for (int dd = 0; dd < 8; ++dd) o[qi][dd] *= sc;
    }

    __syncthreads();   // all waves done reading K -> safe to overwrite with P

    #pragma unroll
    for (int qi = 0; qi < 8; ++qi) {
      pw[qi*128 + lane]      = s0[qi];
      pw[qi*128 + lane + 64] = s1[qi];
    }
    // wave-local ds_write -> ds_read: compiler orders via lgkmcnt, no barrier

    // ---- PV: lane -> (keys j == g mod 8, dims c*8..c*8+7) ----
    #pragma unroll 2
    for (int jj = 0; jj < 16; ++jj) {
      const int j = jj*8 + g;
      const float4 va = *(const float4*)(&vs[j*64 + vo0]);
      const float4 vb = *(const float4*)(&vs[j*64 + vo1]);
      #pragma unroll
      for (int qi = 0; qi < 8; ++qi) {
        const float p = pw[qi*128 + j];      // 8-bank multicast, conflict-free
        o[qi][0] = fmaf(p, va.x, o[qi][0]);
        o[qi][1] = fmaf(p, va.y, o[qi][1]);
        o[qi][2] = fmaf(p, va.z, o[qi][2]);
        o[qi][3] = fmaf(p, va.w, o[qi][3]);
        o[qi][4] = fmaf(p, vb.x, o[qi][4]);
        o[qi][5] = fmaf(p, vb.y, o[qi][5]);
        o[qi][6] = fmaf(p, vb.z, o[qi][6]);
        o[qi][7] = fmaf(p, vb.w, o[qi][7]);
      }
    }
  }

  // ---- reduce partials across the 8 j-groups ----
  #pragma unroll
  for (int qi = 0; qi < 8; ++qi) {
    #pragma unroll
    for (int dd = 0; dd < 8; ++dd) {
      float t = o[qi][dd];
      t += __shfl_xor(t, 8, 64);
      t += __shfl_xor(t, 16, 64);
      t += __shfl_xor(t, 32, 64);
      o[qi][dd] = t;
    }
  }

  // select qi == g with static-index cndmask tree (no dynamic reg indexing)
  float og[8]; float lg = l[0];
  #pragma unroll
  for (int dd = 0; dd < 8; ++dd) og[dd] = o[0][dd];
  #pragma unroll
  for (int qi = 1; qi < 8; ++qi) {
    const bool sel = (g == qi);
    lg = sel ? l[qi] : lg;
    #pragma unroll
    for (int dd = 0; dd < 8; ++dd) og[dd] = sel ? o[qi][dd] : og[dd];
  }
  const float rl = 1.0f / lg;

  float* op = out + ((size_t)(b*Sq + qw + g)*Hq + h)*Dq + c*8;
  float4 oa, ob;
  oa.x = og[0]*rl; oa.y = og[1]*rl; oa.z = og[2]*rl; oa.w = og[3]*rl;
  ob.x = og[4]*rl; ob.y = og[5]*rl; ob.z = og[6]*rl; ob.w = og[7]*rl;
  *(float4*)op       = oa;
  *(float4*)(op + 4) = ob;
}

extern "C" void kernel_launch(void* const* d_in, const int* in_sizes, int n_in,
                              void* d_out, int out_size, void* d_ws, size_t ws_size,
                              hipStream_t stream)
{
  const float* q    = (const float*)d_in[0];
  const float* k    = (const float*)d_in[1];
  const float* v    = (const float*)d_in[2];
  const float* bias = (const float*)d_in[3];
  const int*   mask = (const int*)d_in[4];
  float*       out  = (float*)d_out;

  dim3 grid(Bq*Hq*(Sq/QT));   // 1024 blocks: (b,h) x 32 query-tiles
  attn_fwd<<<grid, dim3(512), 0, stream>>>(q, k, v, bias, mask, out);
}